// Round 1
// baseline (1540.529 us; speedup 1.0000x reference)
//
#include <hip/hip_runtime.h>
#include <math.h>

#define VEC   300
#define HID   256
#define ATT   500
#define NB    64
#define NS    128
#define G3    768     // 3*HID
#define GIC   1536    // both directions packed
#define H2    512     // 2*HID

struct F3 { float x, y, z; };

__device__ __forceinline__ float sigm(float x){ return 1.0f/(1.0f+expf(-x)); }

// ---- prep: Wr[dir][k][u*3+j] = Whh_dir[(j*256+u)*256 + k]  (transposed + gate-interleaved)
__global__ void k_prep(const float* __restrict__ Wf, const float* __restrict__ Wb,
                       float* __restrict__ Wr){
  int o = blockIdx.x*256 + threadIdx.x;
  if (o >= 2*HID*G3) return;
  int c   = o % G3;
  int k   = (o / G3) % HID;
  int dir = o / (G3*HID);
  int u = c/3, j = c - 3*u;
  const float* W = dir ? Wb : Wf;
  Wr[o] = W[(j*HID+u)*HID + k];
}

// ---- input projection GEMM with fused embedding gather.
// C[i][g], i = s*64+b (8192 rows), g in [0,1536): cols 0..767 = Wih_f, 768..1535 = Wih_b.
#define BM 64
#define BN 128
#define BK 64
__global__ __launch_bounds__(256) void k_gi(const int* __restrict__ x,
      const float* __restrict__ emb,
      const float* __restrict__ Wf, const float* __restrict__ Wb,
      const float* __restrict__ bf, const float* __restrict__ bb,
      float* __restrict__ gi){
  __shared__ float As[BK][BM+4];
  __shared__ float Bs[BK][BN+4];
  __shared__ int   xi[BM];
  const int t = threadIdx.x;
  const int row0 = blockIdx.x * BM;
  const int col0 = blockIdx.y * BN;
  if (t < BM) {
    int i = row0 + t; int s = i >> 6; int b = i & 63;
    xi[t] = x[b*NS + s];
  }
  __syncthreads();
  float acc[4][8];
#pragma unroll
  for (int i = 0; i < 4; ++i)
#pragma unroll
    for (int j = 0; j < 8; ++j) acc[i][j] = 0.f;

  const int ty = t >> 4, tx = t & 15;
  for (int ks = 0; ks < 320; ks += BK) {
#pragma unroll
    for (int l = 0; l < 16; ++l) {            // A tile: 64x64
      int idx = l*256 + t;
      int r = idx >> 6, k = idx & 63;
      int kk = ks + k;
      As[k][r] = (kk < VEC) ? emb[(long)xi[r]*VEC + kk] : 0.f;
    }
#pragma unroll
    for (int l = 0; l < 32; ++l) {            // B tile: 128x64 (W rows)
      int idx = l*256 + t;
      int c = idx >> 6, k = idx & 63;
      int kk = ks + k;
      int g = col0 + c;
      float v = 0.f;
      if (kk < VEC) v = (g < G3) ? Wf[(long)g*VEC + kk] : Wb[(long)(g-G3)*VEC + kk];
      Bs[k][c] = v;
    }
    __syncthreads();
#pragma unroll 8
    for (int k = 0; k < BK; ++k) {
      float4 a4 = *reinterpret_cast<const float4*>(&As[k][ty*4]);
      float4 b0 = *reinterpret_cast<const float4*>(&Bs[k][tx*8]);
      float4 b1 = *reinterpret_cast<const float4*>(&Bs[k][tx*8+4]);
      float a[4] = {a4.x, a4.y, a4.z, a4.w};
      float bv[8] = {b0.x,b0.y,b0.z,b0.w,b1.x,b1.y,b1.z,b1.w};
#pragma unroll
      for (int i = 0; i < 4; ++i)
#pragma unroll
        for (int j = 0; j < 8; ++j) acc[i][j] += a[i]*bv[j];
    }
    __syncthreads();
  }
#pragma unroll
  for (int i = 0; i < 4; ++i) {
    int r = row0 + ty*4 + i;
#pragma unroll
    for (int j = 0; j < 8; ++j) {
      int g = col0 + tx*8 + j;
      float bias = (g < G3) ? bf[g] : bb[g-G3];
      gi[(long)r*GIC + g] = acc[i][j] + bias;
    }
  }
}

// ---- GRU scan: one block per (batch-pair, dir). 256 threads = 256 hidden units.
__global__ __launch_bounds__(256) void k_scan(const float* __restrict__ gi,
     const float* __restrict__ Wr,
     const float* __restrict__ bhf, const float* __restrict__ bhb,
     float* __restrict__ hseq){
  __shared__ float hl[2][HID];
  const int t   = threadIdx.x;
  const int dir = blockIdx.x & 1;
  const int b0  = (blockIdx.x >> 1) * 2;
  const float* bhh = dir ? bhb : bhf;
  const F3* W3 = reinterpret_cast<const F3*>(Wr + (long)dir*HID*G3);
  const float bh0 = bhh[t], bh1 = bhh[HID+t], bh2 = bhh[2*HID+t];
  hl[0][t] = 0.f; hl[1][t] = 0.f;
  __syncthreads();
  for (int tt = 0; tt < NS; ++tt) {
    const int s = dir ? (NS-1-tt) : tt;
    float a00=bh0,a01=bh1,a02=bh2, a10=bh0,a11=bh1,a12=bh2;
#pragma unroll 8
    for (int k = 0; k < HID; ++k) {
      F3 w = W3[k*HID + t];
      float h0 = hl[0][k], h1 = hl[1][k];
      a00 += w.x*h0; a01 += w.y*h0; a02 += w.z*h0;
      a10 += w.x*h1; a11 += w.y*h1; a12 += w.z*h1;
    }
    long base = ((long)s*NB + b0)*GIC + dir*G3 + t;
    float i00 = gi[base],       i01 = gi[base+HID],     i02 = gi[base+2*HID];
    float i10 = gi[base+GIC],   i11 = gi[base+GIC+HID], i12 = gi[base+GIC+2*HID];
    float hc0 = hl[0][t], hc1 = hl[1][t];
    __syncthreads();                 // all reads of hl done
    float r0 = sigm(i00+a00), z0 = sigm(i01+a01);
    float n0 = tanhf(i02 + r0*a02);
    float hn0 = (1.f-z0)*n0 + z0*hc0;
    float r1 = sigm(i10+a10), z1 = sigm(i11+a11);
    float n1 = tanhf(i12 + r1*a12);
    float hn1 = (1.f-z1)*n1 + z1*hc1;
    hl[0][t] = hn0; hl[1][t] = hn1;
    hseq[((long)b0*NS + s)*H2 + dir*HID + t]     = hn0;
    hseq[((long)(b0+1)*NS + s)*H2 + dir*HID + t] = hn1;
    __syncthreads();                 // writes visible before next step
  }
}

// ---- attention scores u[b][s] = sum_a tanh(h.W_a + ab_a) * aw[z[b]][a]
__global__ __launch_bounds__(256) void k_att1(const float* __restrict__ hseq,
    const float* __restrict__ afW, const float* __restrict__ afb,
    const float* __restrict__ attw, const int* __restrict__ z,
    float* __restrict__ ub){
  __shared__ float ht[16][H2];        // 32KB
  __shared__ float red[16][260];      // ~16.6KB
  const int t  = threadIdx.x;
  const int b  = blockIdx.x >> 3;
  const int s0 = (blockIdx.x & 7) * 16;
#pragma unroll
  for (int l = 0; l < 32; ++l) {
    int idx = l*256 + t; int sr = idx >> 9; int c = idx & 511;
    ht[sr][c] = hseq[((long)b*NS + s0+sr)*H2 + c];
  }
  __syncthreads();
  float us[16];
#pragma unroll
  for (int s = 0; s < 16; ++s) us[s] = 0.f;
  const int zb = z[b];
  for (int rep = 0; rep < 2; ++rep) {
    int a = rep*256 + t;
    if (a < ATT) {
      const float* wr = afW + (long)a*H2;
      float ab = afb[a];
      float aw = attw[zb*ATT + a];
      float d[16];
#pragma unroll
      for (int s = 0; s < 16; ++s) d[s] = ab;
      for (int h = 0; h < H2; h += 4) {
        float4 w4 = *reinterpret_cast<const float4*>(wr + h);
#pragma unroll
        for (int s = 0; s < 16; ++s) {
          float4 hv = *reinterpret_cast<const float4*>(&ht[s][h]);
          d[s] += w4.x*hv.x + w4.y*hv.y + w4.z*hv.z + w4.w*hv.w;
        }
      }
#pragma unroll
      for (int s = 0; s < 16; ++s) us[s] += tanhf(d[s]) * aw;
    }
  }
#pragma unroll
  for (int s = 0; s < 16; ++s) red[s][t] = us[s];
  __syncthreads();
  for (int off = 128; off >= 1; off >>= 1) {
    if (t < off) {
#pragma unroll
      for (int s = 0; s < 16; ++s) red[s][t] += red[s][t+off];
    }
    __syncthreads();
  }
  if (t < 16) ub[b*NS + s0 + t] = red[t][0];
}

// ---- softmax + pooled + fc
__global__ __launch_bounds__(256) void k_att2(const float* __restrict__ hseq,
   const float* __restrict__ ub, const float* __restrict__ fcW,
   const float* __restrict__ fcb, float* __restrict__ out){
  __shared__ float att[NS];
  __shared__ float red[256];
  __shared__ float pool[H2];
  const int t = threadIdx.x, b = blockIdx.x;
  float v = (t < NS) ? ub[b*NS + t] : -3.4e38f;
  red[t] = v; __syncthreads();
  for (int off = 128; off >= 1; off >>= 1) {
    if (t < off) red[t] = fmaxf(red[t], red[t+off]);
    __syncthreads();
  }
  float mx = red[0]; __syncthreads();
  float e = (t < NS) ? expf(v - mx) : 0.f;
  red[t] = e; __syncthreads();
  for (int off = 128; off >= 1; off >>= 1) {
    if (t < off) red[t] += red[t+off];
    __syncthreads();
  }
  float sm = red[0]; __syncthreads();
  if (t < NS) att[t] = e / sm;
  __syncthreads();
#pragma unroll
  for (int rep = 0; rep < 2; ++rep) {
    int c = rep*256 + t;
    float acc = 0.f;
#pragma unroll 4
    for (int s = 0; s < NS; ++s) acc += att[s] * hseq[((long)b*NS + s)*H2 + c];
    pool[c] = acc;
  }
  __syncthreads();
  for (int j = 0; j < 2; ++j) {
    float p = pool[t]*fcW[j*H2+t] + pool[t+256]*fcW[j*H2+t+256];
    red[t] = p; __syncthreads();
    for (int off = 128; off >= 1; off >>= 1) {
      if (t < off) red[t] += red[t+off];
      __syncthreads();
    }
    if (t == 0) out[b*2+j] = red[0] + fcb[j];
    __syncthreads();
  }
}

extern "C" void kernel_launch(void* const* d_in, const int* in_sizes, int n_in,
                              void* d_out, int out_size, void* d_ws, size_t ws_size,
                              hipStream_t stream) {
  const int*   x     = (const int*)  d_in[0];
  const int*   z     = (const int*)  d_in[1];
  const float* emb   = (const float*)d_in[2];
  const float* Wih_f = (const float*)d_in[3];
  const float* Whh_f = (const float*)d_in[4];
  const float* bih_f = (const float*)d_in[5];
  const float* bhh_f = (const float*)d_in[6];
  const float* Wih_b = (const float*)d_in[7];
  const float* Whh_b = (const float*)d_in[8];
  const float* bih_b = (const float*)d_in[9];
  const float* bhh_b = (const float*)d_in[10];
  const float* afW   = (const float*)d_in[11];
  const float* afb   = (const float*)d_in[12];
  const float* attw  = (const float*)d_in[13];
  const float* fcW   = (const float*)d_in[14];
  const float* fcb   = (const float*)d_in[15];

  float* ws   = (float*)d_ws;
  float* Wr   = ws;                       // 2*256*768      = 393216
  float* giW  = Wr   + 393216;            // 8192*1536      = 12582912
  float* hseq = giW  + 12582912;          // 64*128*512     = 4194304
  float* ubuf = hseq + 4194304;           // 64*128         = 8192

  k_prep<<<dim3(1536), dim3(256), 0, stream>>>(Whh_f, Whh_b, Wr);
  k_gi  <<<dim3(128,12), dim3(256), 0, stream>>>(x, emb, Wih_f, Wih_b, bih_f, bih_b, giW);
  k_scan<<<dim3(64),   dim3(256), 0, stream>>>(giW, Wr, bhh_f, bhh_b, hseq);
  k_att1<<<dim3(512),  dim3(256), 0, stream>>>(hseq, afW, afb, attw, z, ubuf);
  k_att2<<<dim3(64),   dim3(256), 0, stream>>>(hseq, ubuf, fcW, fcb, (float*)d_out);
}

// Round 2
// 1376.663 us; speedup vs baseline: 1.1190x; 1.1190x over previous
//
#include <hip/hip_runtime.h>
#include <math.h>

#define VEC   300
#define HID   256
#define ATT   500
#define NB    64
#define NS    128
#define G3    768     // 3*HID
#define GIC   1536    // both directions packed
#define H2    512     // 2*HID

struct F3 { float x, y, z; };

__device__ __forceinline__ float sigm(float x){ return 1.0f/(1.0f+expf(-x)); }

// ---- prep: Wr[dir][k][u*3+j] = Whh_dir[(j*256+u)*256 + k]  (transposed + gate-interleaved)
__global__ void k_prep(const float* __restrict__ Wf, const float* __restrict__ Wb,
                       float* __restrict__ Wr){
  int o = blockIdx.x*256 + threadIdx.x;
  if (o >= 2*HID*G3) return;
  int c   = o % G3;
  int k   = (o / G3) % HID;
  int dir = o / (G3*HID);
  int u = c/3, j = c - 3*u;
  const float* W = dir ? Wb : Wf;
  Wr[o] = W[(j*HID+u)*HID + k];
}

// ---- input projection GEMM with fused embedding gather.
#define BM 64
#define BN 128
#define BK 64
__global__ __launch_bounds__(256) void k_gi(const int* __restrict__ x,
      const float* __restrict__ emb,
      const float* __restrict__ Wf, const float* __restrict__ Wb,
      const float* __restrict__ bf, const float* __restrict__ bb,
      float* __restrict__ gi){
  __shared__ float As[BK][BM+4];
  __shared__ float Bs[BK][BN+4];
  __shared__ int   xi[BM];
  const int t = threadIdx.x;
  const int row0 = blockIdx.x * BM;
  const int col0 = blockIdx.y * BN;
  if (t < BM) {
    int i = row0 + t; int s = i >> 6; int b = i & 63;
    xi[t] = x[b*NS + s];
  }
  __syncthreads();
  float acc[4][8];
#pragma unroll
  for (int i = 0; i < 4; ++i)
#pragma unroll
    for (int j = 0; j < 8; ++j) acc[i][j] = 0.f;

  const int ty = t >> 4, tx = t & 15;
  for (int ks = 0; ks < 320; ks += BK) {
#pragma unroll
    for (int l = 0; l < 16; ++l) {            // A tile: 64x64
      int idx = l*256 + t;
      int r = idx >> 6, k = idx & 63;
      int kk = ks + k;
      As[k][r] = (kk < VEC) ? emb[(long)xi[r]*VEC + kk] : 0.f;
    }
#pragma unroll
    for (int l = 0; l < 32; ++l) {            // B tile: 128x64 (W rows)
      int idx = l*256 + t;
      int c = idx >> 6, k = idx & 63;
      int kk = ks + k;
      int g = col0 + c;
      float v = 0.f;
      if (kk < VEC) v = (g < G3) ? Wf[(long)g*VEC + kk] : Wb[(long)(g-G3)*VEC + kk];
      Bs[k][c] = v;
    }
    __syncthreads();
#pragma unroll 8
    for (int k = 0; k < BK; ++k) {
      float4 a4 = *reinterpret_cast<const float4*>(&As[k][ty*4]);
      float4 b0 = *reinterpret_cast<const float4*>(&Bs[k][tx*8]);
      float4 b1 = *reinterpret_cast<const float4*>(&Bs[k][tx*8+4]);
      float a[4] = {a4.x, a4.y, a4.z, a4.w};
      float bv[8] = {b0.x,b0.y,b0.z,b0.w,b1.x,b1.y,b1.z,b1.w};
#pragma unroll
      for (int i = 0; i < 4; ++i)
#pragma unroll
        for (int j = 0; j < 8; ++j) acc[i][j] += a[i]*bv[j];
    }
    __syncthreads();
  }
#pragma unroll
  for (int i = 0; i < 4; ++i) {
    int r = row0 + ty*4 + i;
#pragma unroll
    for (int j = 0; j < 8; ++j) {
      int g = col0 + tx*8 + j;
      float bias = (g < G3) ? bf[g] : bb[g-G3];
      gi[(long)r*GIC + g] = acc[i][j] + bias;
    }
  }
}

// ---- GRU scan: one block per (batch-pair, dir). 1024 threads = 256 units x 4 k-quarters.
// 16 waves (4/SIMD) for latency hiding; partial sums exchanged via padded LDS.
__global__ __launch_bounds__(1024) void k_scan(const float* __restrict__ gi,
     const float* __restrict__ Wr,
     const float* __restrict__ bhf, const float* __restrict__ bhb,
     float* __restrict__ hseq){
  __shared__ float hl[2][HID];
  __shared__ float part[HID*25];     // [u][q(4)][b(2)][g(3)] padded to 25/u, ~25.6KB
  const int t   = threadIdx.x;
  const int u   = t & 255;
  const int ks  = t >> 8;            // k-quarter 0..3
  const int dir = blockIdx.x & 1;
  const int b0  = (blockIdx.x >> 1) * 2;
  const float* bhh = dir ? bhb : bhf;
  // W3 base for this thread: rows k = ks*64 .. ks*64+63, column u
  const F3* W3 = reinterpret_cast<const F3*>(Wr + (long)dir*HID*G3) + (long)(ks*64)*HID + u;
  float bh0 = 0.f, bh1 = 0.f, bh2 = 0.f;
  if (ks < 2) { bh0 = bhh[u]; bh1 = bhh[HID+u]; bh2 = bhh[2*HID+u]; }
  if (t < 512) hl[ks][u] = 0.f;
  __syncthreads();

  for (int tt = 0; tt < NS; ++tt) {
    const int s = dir ? (NS-1-tt) : tt;
    // issue gi loads early so they complete under the k-loop
    float i0 = 0.f, i1 = 0.f, i2 = 0.f;
    if (ks < 2) {
      long base = ((long)s*NB + b0 + ks)*GIC + dir*G3 + u;
      i0 = gi[base]; i1 = gi[base+HID]; i2 = gi[base+2*HID];
    }
    float a00=0.f,a01=0.f,a02=0.f, a10=0.f,a11=0.f,a12=0.f;
    const int kb = ks*64;
#pragma unroll 8
    for (int k = 0; k < 64; ++k) {
      F3 w = W3[(long)k*HID];
      float h0 = hl[0][kb+k], h1 = hl[1][kb+k];
      a00 += w.x*h0; a01 += w.y*h0; a02 += w.z*h0;
      a10 += w.x*h1; a11 += w.y*h1; a12 += w.z*h1;
    }
    float hc = (ks < 2) ? hl[ks][u] : 0.f;   // old h for my batch, read before overwrite
    {
      float* p = &part[u*25 + ks*6];
      p[0]=a00; p[1]=a01; p[2]=a02; p[3]=a10; p[4]=a11; p[5]=a12;
    }
    __syncthreads();                         // partials visible; all hl reads done
    if (ks < 2) {
      float g0 = bh0, g1 = bh1, g2 = bh2;
#pragma unroll
      for (int q = 0; q < 4; ++q) {
        const float* p = &part[u*25 + q*6 + ks*3];
        g0 += p[0]; g1 += p[1]; g2 += p[2];
      }
      float r  = sigm(i0 + g0);
      float zg = sigm(i1 + g1);
      float n  = tanhf(i2 + r*g2);
      float hn = (1.f - zg)*n + zg*hc;
      hl[ks][u] = hn;
      hseq[((long)(b0+ks)*NS + s)*H2 + dir*HID + u] = hn;
    }
    __syncthreads();                         // new h visible for next step
  }
}

// ---- attention scores u[b][s] = sum_a tanh(h.W_a + ab_a) * aw[z[b]][a]
__global__ __launch_bounds__(256) void k_att1(const float* __restrict__ hseq,
    const float* __restrict__ afW, const float* __restrict__ afb,
    const float* __restrict__ attw, const int* __restrict__ z,
    float* __restrict__ ub){
  __shared__ float ht[16][H2];        // 32KB
  __shared__ float red[16][260];      // ~16.6KB
  const int t  = threadIdx.x;
  const int b  = blockIdx.x >> 3;
  const int s0 = (blockIdx.x & 7) * 16;
#pragma unroll
  for (int l = 0; l < 32; ++l) {
    int idx = l*256 + t; int sr = idx >> 9; int c = idx & 511;
    ht[sr][c] = hseq[((long)b*NS + s0+sr)*H2 + c];
  }
  __syncthreads();
  float us[16];
#pragma unroll
  for (int s = 0; s < 16; ++s) us[s] = 0.f;
  const int zb = z[b];
  for (int rep = 0; rep < 2; ++rep) {
    int a = rep*256 + t;
    if (a < ATT) {
      const float* wr = afW + (long)a*H2;
      float ab = afb[a];
      float aw = attw[zb*ATT + a];
      float d[16];
#pragma unroll
      for (int s = 0; s < 16; ++s) d[s] = ab;
      for (int h = 0; h < H2; h += 4) {
        float4 w4 = *reinterpret_cast<const float4*>(wr + h);
#pragma unroll
        for (int s = 0; s < 16; ++s) {
          float4 hv = *reinterpret_cast<const float4*>(&ht[s][h]);
          d[s] += w4.x*hv.x + w4.y*hv.y + w4.z*hv.z + w4.w*hv.w;
        }
      }
#pragma unroll
      for (int s = 0; s < 16; ++s) us[s] += tanhf(d[s]) * aw;
    }
  }
#pragma unroll
  for (int s = 0; s < 16; ++s) red[s][t] = us[s];
  __syncthreads();
  for (int off = 128; off >= 1; off >>= 1) {
    if (t < off) {
#pragma unroll
      for (int s = 0; s < 16; ++s) red[s][t] += red[s][t+off];
    }
    __syncthreads();
  }
  if (t < 16) ub[b*NS + s0 + t] = red[t][0];
}

// ---- softmax + pooled + fc
__global__ __launch_bounds__(256) void k_att2(const float* __restrict__ hseq,
   const float* __restrict__ ub, const float* __restrict__ fcW,
   const float* __restrict__ fcb, float* __restrict__ out){
  __shared__ float att[NS];
  __shared__ float red[256];
  __shared__ float pool[H2];
  const int t = threadIdx.x, b = blockIdx.x;
  float v = (t < NS) ? ub[b*NS + t] : -3.4e38f;
  red[t] = v; __syncthreads();
  for (int off = 128; off >= 1; off >>= 1) {
    if (t < off) red[t] = fmaxf(red[t], red[t+off]);
    __syncthreads();
  }
  float mx = red[0]; __syncthreads();
  float e = (t < NS) ? expf(v - mx) : 0.f;
  red[t] = e; __syncthreads();
  for (int off = 128; off >= 1; off >>= 1) {
    if (t < off) red[t] += red[t+off];
    __syncthreads();
  }
  float sm = red[0]; __syncthreads();
  if (t < NS) att[t] = e / sm;
  __syncthreads();
#pragma unroll
  for (int rep = 0; rep < 2; ++rep) {
    int c = rep*256 + t;
    float acc = 0.f;
#pragma unroll 4
    for (int s = 0; s < NS; ++s) acc += att[s] * hseq[((long)b*NS + s)*H2 + c];
    pool[c] = acc;
  }
  __syncthreads();
  for (int j = 0; j < 2; ++j) {
    float p = pool[t]*fcW[j*H2+t] + pool[t+256]*fcW[j*H2+t+256];
    red[t] = p; __syncthreads();
    for (int off = 128; off >= 1; off >>= 1) {
      if (t < off) red[t] += red[t+off];
      __syncthreads();
    }
    if (t == 0) out[b*2+j] = red[0] + fcb[j];
    __syncthreads();
  }
}

extern "C" void kernel_launch(void* const* d_in, const int* in_sizes, int n_in,
                              void* d_out, int out_size, void* d_ws, size_t ws_size,
                              hipStream_t stream) {
  const int*   x     = (const int*)  d_in[0];
  const int*   z     = (const int*)  d_in[1];
  const float* emb   = (const float*)d_in[2];
  const float* Wih_f = (const float*)d_in[3];
  const float* Whh_f = (const float*)d_in[4];
  const float* bih_f = (const float*)d_in[5];
  const float* bhh_f = (const float*)d_in[6];
  const float* Wih_b = (const float*)d_in[7];
  const float* Whh_b = (const float*)d_in[8];
  const float* bih_b = (const float*)d_in[9];
  const float* bhh_b = (const float*)d_in[10];
  const float* afW   = (const float*)d_in[11];
  const float* afb   = (const float*)d_in[12];
  const float* attw  = (const float*)d_in[13];
  const float* fcW   = (const float*)d_in[14];
  const float* fcb   = (const float*)d_in[15];

  float* ws   = (float*)d_ws;
  float* Wr   = ws;                       // 2*256*768      = 393216
  float* giW  = Wr   + 393216;            // 8192*1536      = 12582912
  float* hseq = giW  + 12582912;          // 64*128*512     = 4194304
  float* ubuf = hseq + 4194304;           // 64*128         = 8192

  k_prep<<<dim3(1536), dim3(256), 0, stream>>>(Whh_f, Whh_b, Wr);
  k_gi  <<<dim3(128,12), dim3(256), 0, stream>>>(x, emb, Wih_f, Wih_b, bih_f, bih_b, giW);
  k_scan<<<dim3(64),   dim3(1024), 0, stream>>>(giW, Wr, bhh_f, bhh_b, hseq);
  k_att1<<<dim3(512),  dim3(256), 0, stream>>>(hseq, afW, afb, attw, z, ubuf);
  k_att2<<<dim3(64),   dim3(256), 0, stream>>>(hseq, ubuf, fcW, fcb, (float*)d_out);
}